// Round 1
// baseline (18296.681 us; speedup 1.0000x reference)
//
#include <hip/hip_runtime.h>
#include <math.h>

// ---------------- constants ----------------
#define HH 45
#define WW 90
#define CC 768
#define NTOK 4050           // 45*90
#define KW 23               // kept W-frequencies
#define NROW 1035           // 45*23
#define NKF 385             // rfft length along C: 768/2+1
#define SZ_ALL 3110400.0f   // 45*90*768
#define LAMF 0.01f

// ---------------- LN ----------------
__global__ __launch_bounds__(256) void ln_kernel(const float* __restrict__ x,
                                                 const float* __restrict__ w,
                                                 const float* __restrict__ b,
                                                 float* __restrict__ y) {
    __shared__ float red[256];
    int t = blockIdx.x;
    int tid = threadIdx.x;
    const float* row = x + (size_t)t * 768;
    float v0 = row[tid], v1 = row[tid + 256], v2 = row[tid + 512];
    red[tid] = v0 + v1 + v2;
    __syncthreads();
    for (int off = 128; off > 0; off >>= 1) {
        if (tid < off) red[tid] += red[tid + off];
        __syncthreads();
    }
    float mean = red[0] * (1.0f / 768.0f);
    __syncthreads();
    float d0 = v0 - mean, d1 = v1 - mean, d2 = v2 - mean;
    red[tid] = d0 * d0 + d1 * d1 + d2 * d2;
    __syncthreads();
    for (int off = 128; off > 0; off >>= 1) {
        if (tid < off) red[tid] += red[tid + off];
        __syncthreads();
    }
    float rstd = rsqrtf(red[0] * (1.0f / 768.0f) + 1e-5f);
    float* yr = y + (size_t)t * 768;
    yr[tid]       = d0 * rstd * w[tid]       + b[tid];
    yr[tid + 256] = d1 * rstd * w[tid + 256] + b[tid + 256];
    yr[tid + 512] = d2 * rstd * w[tid + 512] + b[tid + 512];
}

// ---------------- tables (DFT twiddles; double trig for accuracy) ----------------
__global__ __launch_bounds__(256) void init_tables(float* TCc, float* TCs, float* TWc,
                                                   float* TWs, float* THc, float* THs) {
    int gid = blockIdx.x * 256 + threadIdx.x;
    const double TP = 6.283185307179586476925286766559;
    if (gid < 385 * 768) {
        int n = gid / 768, c = gid % 768;
        int r = (n * c) % 768;
        double a = TP * (double)r / 768.0;
        TCc[gid] = (float)cos(a);
        TCs[gid] = (float)sin(a);
    }
    if (gid < 90 * 90) {
        int n = gid / 90, ww = gid % 90;
        int r = (n * ww) % 90;
        double a = TP * (double)r / 90.0;
        TWc[gid] = (float)cos(a);
        TWs[gid] = (float)sin(a);
    }
    if (gid < 45 * 45) {
        int n = gid / 45, hh = gid % 45;
        int r = (n * hh) % 45;
        double a = TP * (double)r / 45.0;
        THc[gid] = (float)cos(a);
        THs[gid] = (float)sin(a);
    }
}

// ---------------- Wp/Wm/Vp/Vm prep per layer ----------------
__global__ __launch_bounds__(256) void wpm_prep(const float* __restrict__ w1l,
                                                const float* __restrict__ w2l,
                                                float* Wp, float* Wm, float* Vp, float* Vm) {
    int i = blockIdx.x * 256 + threadIdx.x;
    if (i < 73728) {
        float a = w1l[i], b = w1l[73728 + i];
        Wp[i] = 0.5f * (a + b);
        Wm[i] = 0.5f * (a - b);
        float c = w2l[i], d = w2l[73728 + i];
        Vp[i] = 0.5f * (c + d);
        Vm[i] = 0.5f * (c - d);
    }
}

// ---------------- generic fp32 tile GEMM: C = A[MxK] * B[NxK]^T (+epilogues) ----------------
// amode: 0 = A row-major [M,K]; 1 = patch gather from x (1,20,720,1440)
// emode: 0 = out = acc + bias[n] + extra[m*N+n]   (patch embed w/ pos; fc2 w/ residual)
//        1 = out = gelu(acc + bias[n])            (fc1)
//        3 = head scatter into (20,720,1440)
__global__ __launch_bounds__(256) void gemm_f32(const float* __restrict__ A,
                                                const float* __restrict__ B,
                                                const float* __restrict__ bias,
                                                const float* __restrict__ extra,
                                                float* __restrict__ C,
                                                int M, int N, int K, int amode, int emode) {
    __shared__ float As[16][65];
    __shared__ float Bs[16][65];
    int tid = threadIdx.x;
    int tx = tid & 15, ty = tid >> 4;
    int m0 = blockIdx.x * 64, n0 = blockIdx.y * 64;
    float acc[4][4] = {};
    int lr = tid >> 2, lq = tid & 3;
    for (int k0 = 0; k0 < K; k0 += 16) {
        float4 av = make_float4(0.f, 0.f, 0.f, 0.f);
        int am = m0 + lr;
        if (am < M) {
            if (amode == 0) {
                av = *(const float4*)(A + (size_t)am * K + k0 + lq * 4);
            } else {
                int gh = am / 90, gw = am % 90;
                int k = k0 + lq * 4;
                int c = k >> 8, ph = (k >> 4) & 15, pw = k & 15;
                av = *(const float4*)(A + (size_t)c * 1036800 +
                                      (size_t)(gh * 16 + ph) * 1440 + gw * 16 + pw);
            }
        }
        As[lq * 4 + 0][lr] = av.x;
        As[lq * 4 + 1][lr] = av.y;
        As[lq * 4 + 2][lr] = av.z;
        As[lq * 4 + 3][lr] = av.w;
        float4 bv = make_float4(0.f, 0.f, 0.f, 0.f);
        int bn = n0 + lr;
        if (bn < N) bv = *(const float4*)(B + (size_t)bn * K + k0 + lq * 4);
        Bs[lq * 4 + 0][lr] = bv.x;
        Bs[lq * 4 + 1][lr] = bv.y;
        Bs[lq * 4 + 2][lr] = bv.z;
        Bs[lq * 4 + 3][lr] = bv.w;
        __syncthreads();
#pragma unroll
        for (int kk = 0; kk < 16; kk++) {
            float a_[4], b_[4];
#pragma unroll
            for (int i = 0; i < 4; i++) a_[i] = As[kk][ty + 16 * i];
#pragma unroll
            for (int j = 0; j < 4; j++) b_[j] = Bs[kk][tx + 16 * j];
#pragma unroll
            for (int i = 0; i < 4; i++)
#pragma unroll
                for (int j = 0; j < 4; j++) acc[i][j] += a_[i] * b_[j];
        }
        __syncthreads();
    }
#pragma unroll
    for (int i = 0; i < 4; i++) {
        int m = m0 + ty + 16 * i;
        if (m >= M) continue;
#pragma unroll
        for (int j = 0; j < 4; j++) {
            int n = n0 + tx + 16 * j;
            if (n >= N) continue;
            float v = acc[i][j];
            if (emode == 0) {
                v += bias[n] + extra[(size_t)m * N + n];
                C[(size_t)m * N + n] = v;
            } else if (emode == 1) {
                v += bias[n];
                C[(size_t)m * N + n] = 0.5f * v * (1.0f + erff(v * 0.70710678118654752f));
            } else {
                int ch = n % 20, q = n / 20;
                int pw = q & 15, ph = q >> 4;
                int gh = m / 90, gw = m % 90;
                C[(size_t)ch * 1036800 + (size_t)(gh * 16 + ph) * 1440 + gw * 16 + pw] = v;
            }
        }
    }
}

// ---------------- DFT along C (real -> complex, k in [0,385)), dual-acc GEMM ----------------
// out_re[m*385+k] = sum_c A[m,c] cos ; out_im = -sum_c A[m,c] sin
__global__ __launch_bounds__(256) void gemm_dht_c(const float* __restrict__ A,
                                                  const float* __restrict__ Bc,
                                                  const float* __restrict__ Bs,
                                                  float* __restrict__ outRe,
                                                  float* __restrict__ outIm, int M) {
    const int K = 768, N = 385;
    __shared__ float As[16][65];
    __shared__ float Bcs[16][65];
    __shared__ float Bss[16][65];
    int tid = threadIdx.x;
    int tx = tid & 15, ty = tid >> 4;
    int m0 = blockIdx.x * 64, n0 = blockIdx.y * 64;
    float accR[4][4] = {}, accI[4][4] = {};
    int lr = tid >> 2, lq = tid & 3;
    for (int k0 = 0; k0 < K; k0 += 16) {
        float4 av = make_float4(0.f, 0.f, 0.f, 0.f);
        int am = m0 + lr;
        if (am < M) av = *(const float4*)(A + (size_t)am * K + k0 + lq * 4);
        As[lq * 4 + 0][lr] = av.x;
        As[lq * 4 + 1][lr] = av.y;
        As[lq * 4 + 2][lr] = av.z;
        As[lq * 4 + 3][lr] = av.w;
        float4 cv = make_float4(0.f, 0.f, 0.f, 0.f);
        float4 sv = make_float4(0.f, 0.f, 0.f, 0.f);
        int bn = n0 + lr;
        if (bn < N) {
            cv = *(const float4*)(Bc + (size_t)bn * K + k0 + lq * 4);
            sv = *(const float4*)(Bs + (size_t)bn * K + k0 + lq * 4);
        }
        Bcs[lq * 4 + 0][lr] = cv.x;
        Bcs[lq * 4 + 1][lr] = cv.y;
        Bcs[lq * 4 + 2][lr] = cv.z;
        Bcs[lq * 4 + 3][lr] = cv.w;
        Bss[lq * 4 + 0][lr] = sv.x;
        Bss[lq * 4 + 1][lr] = sv.y;
        Bss[lq * 4 + 2][lr] = sv.z;
        Bss[lq * 4 + 3][lr] = sv.w;
        __syncthreads();
#pragma unroll
        for (int kk = 0; kk < 16; kk++) {
            float a_[4], c_[4], s_[4];
#pragma unroll
            for (int i = 0; i < 4; i++) a_[i] = As[kk][ty + 16 * i];
#pragma unroll
            for (int j = 0; j < 4; j++) {
                c_[j] = Bcs[kk][tx + 16 * j];
                s_[j] = Bss[kk][tx + 16 * j];
            }
#pragma unroll
            for (int i = 0; i < 4; i++)
#pragma unroll
                for (int j = 0; j < 4; j++) {
                    accR[i][j] += a_[i] * c_[j];
                    accI[i][j] += a_[i] * s_[j];
                }
        }
        __syncthreads();
    }
#pragma unroll
    for (int i = 0; i < 4; i++) {
        int m = m0 + ty + 16 * i;
        if (m >= M) continue;
#pragma unroll
        for (int j = 0; j < 4; j++) {
            int n = n0 + tx + 16 * j;
            if (n >= N) continue;
            size_t g = (size_t)m * 385 + n;
            outRe[g] = accR[i][j];
            outIm[g] = -accI[i][j];
        }
    }
}

// ---------------- DFT along W: in [h][Win][385] -> out [h][Jout][385] ----------------
// modeA=1: wfreq(j) = j<23 ? j : j+45  (DHT1: 45 selected cols); modeA=0: wfreq=j (DHT2: all 90)
__global__ __launch_bounds__(256) void dft_w_kernel(const float* __restrict__ inre,
                                                    const float* __restrict__ inim,
                                                    float* __restrict__ outre,
                                                    float* __restrict__ outim,
                                                    const float* __restrict__ twc,
                                                    const float* __restrict__ tws,
                                                    int Win, int Jout, int modeA) {
    int h = blockIdx.x;
    int k0 = blockIdx.y * 32;
    __shared__ float sre[2880];
    __shared__ float sim[2880];
    for (int idx = threadIdx.x; idx < Win * 32; idx += 256) {
        int w = idx >> 5, kk = idx & 31;
        int k = k0 + kk;
        float vr = 0.f, vi = 0.f;
        if (k < 385) {
            size_t g = ((size_t)h * Win + w) * 385 + k;
            vr = inre[g];
            vi = inim[g];
        }
        sre[idx] = vr;
        sim[idx] = vi;
    }
    __syncthreads();
    for (int idx = threadIdx.x; idx < Jout * 32; idx += 256) {
        int j = idx >> 5, kk = idx & 31;
        int k = k0 + kk;
        if (k >= 385) continue;
        int wf = modeA ? (j < 23 ? j : j + 45) : j;
        float ar = 0.f, ai = 0.f;
        for (int ww = 0; ww < Win; ww++) {
            float cc = twc[wf * 90 + ww], ss = tws[wf * 90 + ww];
            float xr = sre[(ww << 5) | kk], xi = sim[(ww << 5) | kk];
            ar += xr * cc + xi * ss;
            ai += xi * cc - xr * ss;
        }
        size_t g = ((size_t)h * Jout + j) * 385 + k;
        outre[g] = ar;
        outim[g] = ai;
    }
}

// ---------------- DFT along H: in [45][J][385] -> out [45][J][385] ----------------
__global__ __launch_bounds__(256) void dft_h_kernel(const float* __restrict__ inre,
                                                    const float* __restrict__ inim,
                                                    float* __restrict__ outre,
                                                    float* __restrict__ outim,
                                                    const float* __restrict__ thc,
                                                    const float* __restrict__ ths, int J) {
    int j = blockIdx.x;
    int k0 = blockIdx.y * 32;
    __shared__ float sre[1440];
    __shared__ float sim[1440];
    for (int idx = threadIdx.x; idx < 45 * 32; idx += 256) {
        int hh = idx >> 5, kk = idx & 31;
        int k = k0 + kk;
        float vr = 0.f, vi = 0.f;
        if (k < 385) {
            size_t g = ((size_t)hh * J + j) * 385 + k;
            vr = inre[g];
            vi = inim[g];
        }
        sre[idx] = vr;
        sim[idx] = vi;
    }
    __syncthreads();
    for (int idx = threadIdx.x; idx < 45 * 32; idx += 256) {
        int i = idx >> 5, kk = idx & 31;
        int k = k0 + kk;
        if (k >= 385) continue;
        float ar = 0.f, ai = 0.f;
        for (int hh = 0; hh < 45; hh++) {
            float cc = thc[i * 45 + hh], ss = ths[i * 45 + hh];
            float xr = sre[(hh << 5) | kk], xi = sim[(hh << 5) | kk];
            ar += xr * cc + xi * ss;
            ai += xi * cc - xr * ss;
        }
        size_t g = ((size_t)i * J + j) * 385 + k;
        outre[g] = ar;
        outim[g] = ai;
    }
}

// ---------------- build a (DHT1 slice via Hermitian symmetry) and n (negated-index gather) ----
__global__ __launch_bounds__(256) void build_an(const float* __restrict__ F3re,
                                                const float* __restrict__ F3im,
                                                const float* __restrict__ tln,
                                                float* __restrict__ a, float* __restrict__ nb) {
    int idx = blockIdx.x * 256 + threadIdx.x;
    if (idx >= NROW * 768) return;
    int c = idx % 768;
    int r = idx / 768;
    int h = r / KW, w0 = r % KW;
    int h2 = (45 - h) % 45, w2 = (90 - w0) % 90;
    float av;
    if (c <= 384) {
        size_t g = ((size_t)(h * 45 + w0)) * 385 + c;
        av = F3re[g] + F3im[g];
    } else {
        int k = 768 - c;
        int j2 = (w2 == 0) ? 0 : (w2 - 45);
        size_t g = ((size_t)(h2 * 45 + j2)) * 385 + k;
        av = F3re[g] - F3im[g];
    }
    a[idx] = av;
    nb[idx] = tln[((size_t)(h2 * 90 + w2)) * 768 + c];
}

// ---------------- block-diagonal MLP (96x96 per block) ----------------
// mode 1: outA=relu(A*WP+Bm*WM+bA), outB=relu(Bm*WP+A*WM+bB)
// mode 2: outA = A*WP + Bm*WM + bA
// mode 3: o2n = A*WP + Bm*WM + bA;  outA = softthresh(o2n + Bm[r][o])
__global__ __launch_bounds__(256) void blk_mm(const float* __restrict__ A,
                                              const float* __restrict__ Bm,
                                              const float* __restrict__ WP,
                                              const float* __restrict__ WM,
                                              const float* __restrict__ bA,
                                              const float* __restrict__ bB,
                                              float* __restrict__ outA,
                                              float* __restrict__ outB, int mode) {
    int b = blockIdx.x;
    int r0 = blockIdx.y * 64;
    __shared__ float sa[64 * 96];
    __shared__ float sn[64 * 96];
    for (int idx = threadIdx.x; idx < 64 * 96; idx += 256) {
        int r = idx / 96, c = idx % 96;
        int row = r0 + r;
        float va = 0.f, vb = 0.f;
        if (row < NROW) {
            va = A[(size_t)row * 768 + b * 96 + c];
            vb = Bm[(size_t)row * 768 + b * 96 + c];
        }
        sa[idx] = va;
        sn[idx] = vb;
    }
    __syncthreads();
    for (int idx = threadIdx.x; idx < 64 * 96; idx += 256) {
        int r = idx / 96, o = idx % 96;
        int row = r0 + r;
        if (row >= NROW) continue;
        float acc1 = bA[b * 96 + o];
        float acc2 = (mode == 1) ? bB[b * 96 + o] : 0.f;
        for (int i = 0; i < 96; i++) {
            float wp = WP[(b * 96 + i) * 96 + o];
            float wm = WM[(b * 96 + i) * 96 + o];
            float av = sa[r * 96 + i];
            float nv = sn[r * 96 + i];
            acc1 += av * wp + nv * wm;
            if (mode == 1) acc2 += nv * wp + av * wm;
        }
        size_t g = (size_t)row * 768 + b * 96 + o;
        if (mode == 1) {
            outA[g] = fmaxf(acc1, 0.f);
            outB[g] = fmaxf(acc2, 0.f);
        } else if (mode == 2) {
            outA[g] = acc1;
        } else {
            float full = acc1 + sn[r * 96 + o];
            float v = (full > LAMF) ? (full - LAMF) : ((full < -LAMF) ? (full + LAMF) : 0.f);
            outA[g] = v;
        }
    }
}

// ---------------- combine: mid = cur + tln + DHT2/size  (symmetry reconstruction) ------------
__global__ __launch_bounds__(256) void afno_combine(const float* __restrict__ F4re,
                                                    const float* __restrict__ F4im,
                                                    const float* __restrict__ cur,
                                                    const float* __restrict__ tln,
                                                    float* __restrict__ mid) {
    int idx = blockIdx.x * 256 + threadIdx.x;
    if (idx >= 3110400) return;
    int c = idx % 768;
    int t = idx / 768;
    int h = t / 90, w0 = t % 90;
    float v;
    if (c <= 384) {
        size_t g = (size_t)t * 385 + c;
        v = F4re[g] + F4im[g];
    } else {
        int k = 768 - c;
        int h2 = (45 - h) % 45, w2 = (90 - w0) % 90;
        size_t g = ((size_t)(h2 * 90 + w2)) * 385 + k;
        v = F4re[g] - F4im[g];
    }
    mid[idx] = cur[idx] + tln[idx] + v * (1.0f / SZ_ALL);
}

// ---------------- host ----------------
extern "C" void kernel_launch(void* const* d_in, const int* in_sizes, int n_in,
                              void* d_out, int out_size, void* d_ws, size_t ws_size,
                              hipStream_t stream) {
    const float* x       = (const float*)d_in[0];
    const float* patch_w = (const float*)d_in[1];
    const float* patch_b = (const float*)d_in[2];
    const float* pos     = (const float*)d_in[3];
    const float* n1w     = (const float*)d_in[4];
    const float* n1b     = (const float*)d_in[5];
    const float* w1      = (const float*)d_in[6];
    const float* b1      = (const float*)d_in[7];
    const float* w2      = (const float*)d_in[8];
    const float* b2      = (const float*)d_in[9];
    const float* n2w     = (const float*)d_in[10];
    const float* n2b     = (const float*)d_in[11];
    const float* fc1w    = (const float*)d_in[12];
    const float* fc1b    = (const float*)d_in[13];
    const float* fc2w    = (const float*)d_in[14];
    const float* fc2b    = (const float*)d_in[15];
    const float* headw   = (const float*)d_in[16];
    float* out = (float*)d_out;
    float* wsp = (float*)d_ws;

    // ws layout (floats), all sizes rounded to multiples of 4 for float4 alignment
    size_t off = 0;
    auto alloc = [&](size_t n) {
        float* p = wsp + off;
        off += (n + 3) & ~(size_t)3;
        return p;
    };
    float* TCc = alloc(295680);
    float* TCs = alloc(295680);
    float* TWc = alloc(8100);
    float* TWs = alloc(8100);
    float* THc = alloc(2025);
    float* THs = alloc(2025);
    float* Wp = alloc(73728);
    float* Wm = alloc(73728);
    float* Vp = alloc(73728);
    float* Vm = alloc(73728);
    float* cur = alloc(3110400);
    float* tln = alloc(3110400);
    float* mid = alloc(3110400);
    size_t region = off;
    // AFNO scratch region (also reused as MLP hidden in the non-overlapping phase)
    float* P1re = wsp + region;
    float* P1im = P1re + 1559252;
    float* P2re = P1im + 1559252;
    float* P2im = P2re + 1559252;
    float* F2re = P2im + 1559252;
    float* F2im = F2re + 779628;
    float* F3re = F2im + 779628;
    float* F3im = F3re + 779628;
    float* abuf = F3im + 779628;
    float* nbuf = abuf + 794880;
    float* o1k = nbuf + 794880;
    float* o1n = o1k + 794880;
    float* o2k = o1n + 794880;
    float* ybuf = o2k + 794880;
    float* hidden = wsp + region;  // 12,441,600 floats, fits inside AFNO scratch (14.1M)
    size_t need = (region + 14124808) * sizeof(float);
    if (ws_size < need) return;  // visible failure rather than corruption

    init_tables<<<1155, 256, 0, stream>>>(TCc, TCs, TWc, TWs, THc, THs);

    // patch embed: cur = patches @ patch_w^T + patch_b + pos
    gemm_f32<<<dim3(64, 12), 256, 0, stream>>>(x, patch_w, patch_b, pos, cur,
                                               NTOK, 768, 5120, 1, 0);

    for (int l = 0; l < 12; l++) {
        const float* w1l = w1 + (size_t)l * 147456;
        const float* b1l = b1 + (size_t)l * 1536;
        const float* w2l = w2 + (size_t)l * 147456;
        const float* b2l = b2 + (size_t)l * 1536;

        wpm_prep<<<288, 256, 0, stream>>>(w1l, w2l, Wp, Wm, Vp, Vm);
        ln_kernel<<<NTOK, 256, 0, stream>>>(cur, n1w + l * 768, n1b + l * 768, tln);

        // DHT1: C-axis rfft -> W-axis (45 selected cols) -> H-axis
        gemm_dht_c<<<dim3(64, 7), 256, 0, stream>>>(tln, TCc, TCs, P1re, P1im, NTOK);
        dft_w_kernel<<<dim3(45, 13), 256, 0, stream>>>(P1re, P1im, F2re, F2im, TWc, TWs,
                                                       90, 45, 1);
        dft_h_kernel<<<dim3(45, 13), 256, 0, stream>>>(F2re, F2im, F3re, F3im, THc, THs, 45);
        build_an<<<(NROW * 768 + 255) / 256, 256, 0, stream>>>(F3re, F3im, tln, abuf, nbuf);

        // block MLP
        blk_mm<<<dim3(8, 17), 256, 0, stream>>>(abuf, nbuf, Wp, Wm, b1l, b1l + 768,
                                                o1k, o1n, 1);
        blk_mm<<<dim3(8, 17), 256, 0, stream>>>(o1k, o1n, Vp, Vm, b2l, nullptr,
                                                o2k, nullptr, 2);
        blk_mm<<<dim3(8, 17), 256, 0, stream>>>(o1n, o2k, Vp, Vm, b2l + 768, nullptr,
                                                ybuf, nullptr, 3);

        // DHT2: C-axis rfft (1035 rows) -> W-axis (23 -> 90) -> H-axis, then combine
        gemm_dht_c<<<dim3(17, 7), 256, 0, stream>>>(ybuf, TCc, TCs, F2re, F2im, NROW);
        dft_w_kernel<<<dim3(45, 13), 256, 0, stream>>>(F2re, F2im, P1re, P1im, TWc, TWs,
                                                       23, 90, 0);
        dft_h_kernel<<<dim3(90, 13), 256, 0, stream>>>(P1re, P1im, P2re, P2im, THc, THs, 90);
        afno_combine<<<(3110400 + 255) / 256, 256, 0, stream>>>(P2re, P2im, cur, tln, mid);

        // MLP
        ln_kernel<<<NTOK, 256, 0, stream>>>(mid, n2w + l * 768, n2b + l * 768, tln);
        gemm_f32<<<dim3(64, 48), 256, 0, stream>>>(tln, fc1w + (size_t)l * 2359296,
                                                   fc1b + l * 3072, nullptr, hidden,
                                                   NTOK, 3072, 768, 0, 1);
        gemm_f32<<<dim3(64, 12), 256, 0, stream>>>(hidden, fc2w + (size_t)l * 2359296,
                                                   fc2b + l * 768, mid, cur,
                                                   NTOK, 768, 3072, 0, 0);
    }

    // head + scatter to (20,720,1440)
    gemm_f32<<<dim3(64, 80), 256, 0, stream>>>(cur, headw, nullptr, nullptr, out,
                                               NTOK, 5120, 768, 0, 3);
}

// Round 2
// 7038.792 us; speedup vs baseline: 2.5994x; 2.5994x over previous
//
#include <hip/hip_runtime.h>
#include <math.h>

typedef __attribute__((ext_vector_type(4))) float floatx4;
typedef __attribute__((ext_vector_type(8))) short bf16x8;
typedef unsigned short u16;

#define HH 45
#define WW 90
#define NTOK 4050
#define KW 23
#define NROW 1035
#define SZ_ALL 3110400.0f
#define LAMF 0.01f

#define GLP(p) ((const __attribute__((address_space(1))) void*)(p))
#define LDSP(p) ((__attribute__((address_space(3))) void*)(p))

__device__ __forceinline__ u16 f2b(float f) {
    union { float f; unsigned int u; } x;
    x.f = f;
    unsigned int r = x.u + 0x7FFFu + ((x.u >> 16) & 1u);
    return (u16)(r >> 16);
}

// ---------------- LN (fp32 out + bf16 out) ----------------
__global__ __launch_bounds__(256) void ln_kernel(const float* __restrict__ x,
                                                 const float* __restrict__ w,
                                                 const float* __restrict__ b,
                                                 float* __restrict__ y,
                                                 u16* __restrict__ y16) {
    __shared__ float red[256];
    int t = blockIdx.x;
    int tid = threadIdx.x;
    const float* row = x + (size_t)t * 768;
    float v0 = row[tid], v1 = row[tid + 256], v2 = row[tid + 512];
    red[tid] = v0 + v1 + v2;
    __syncthreads();
    for (int off = 128; off > 0; off >>= 1) {
        if (tid < off) red[tid] += red[tid + off];
        __syncthreads();
    }
    float mean = red[0] * (1.0f / 768.0f);
    __syncthreads();
    float d0 = v0 - mean, d1 = v1 - mean, d2 = v2 - mean;
    red[tid] = d0 * d0 + d1 * d1 + d2 * d2;
    __syncthreads();
    for (int off = 128; off > 0; off >>= 1) {
        if (tid < off) red[tid] += red[tid + off];
        __syncthreads();
    }
    float rstd = rsqrtf(red[0] * (1.0f / 768.0f) + 1e-5f);
    float* yr = y + (size_t)t * 768;
    u16* ys = y16 + (size_t)t * 768;
    float o0 = d0 * rstd * w[tid] + b[tid];
    float o1 = d1 * rstd * w[tid + 256] + b[tid + 256];
    float o2 = d2 * rstd * w[tid + 512] + b[tid + 512];
    yr[tid] = o0; yr[tid + 256] = o1; yr[tid + 512] = o2;
    ys[tid] = f2b(o0); ys[tid + 256] = f2b(o1); ys[tid + 512] = f2b(o2);
}

// ---------------- tables ----------------
__global__ __launch_bounds__(256) void init_tables(u16* TCc, u16* TCs, float* TWc,
                                                   float* TWs, float* THc, float* THs) {
    int gid = blockIdx.x * 256 + threadIdx.x;
    const double TP = 6.283185307179586476925286766559;
    if (gid < 512 * 768) {
        int n = gid / 768, c = gid % 768;
        int r = (n * c) % 768;
        double a = TP * (double)r / 768.0;
        TCc[gid] = f2b((float)cos(a));
        TCs[gid] = f2b((float)(-sin(a)));
    }
    if (gid < 90 * 90) {
        int n = gid / 90, ww = gid % 90;
        int r = (n * ww) % 90;
        double a = TP * (double)r / 90.0;
        TWc[gid] = (float)cos(a);
        TWs[gid] = (float)sin(a);
    }
    if (gid < 45 * 45) {
        int n = gid / 45, hh = gid % 45;
        int r = (n * hh) % 45;
        double a = TP * (double)r / 45.0;
        THc[gid] = (float)cos(a);
        THs[gid] = (float)sin(a);
    }
}

// ---------------- fp32 -> bf16 cast (n multiple of 4) ----------------
__global__ __launch_bounds__(256) void cast_f2b(const float* __restrict__ in,
                                                u16* __restrict__ out, int n) {
    int i = (blockIdx.x * 256 + threadIdx.x) * 4;
    if (i >= n) return;
    float4 v = *(const float4*)(in + i);
    out[i] = f2b(v.x); out[i + 1] = f2b(v.y); out[i + 2] = f2b(v.z); out[i + 3] = f2b(v.w);
}

// ---------------- packed block-MLP weights ----------------
// WB1k[b][o][i] = i<96 ? Wp : Wm ; WB1n = i<96 ? Wm : Wp ; WB2 = i<96 ? Vp : Vm
__global__ __launch_bounds__(256) void wpm_prep(const float* __restrict__ w1l,
                                                const float* __restrict__ w2l,
                                                u16* WB1k, u16* WB1n, u16* WB2) {
    int i = blockIdx.x * 256 + threadIdx.x;
    if (i >= 147456) return;
    int ii = i % 192;
    int o = (i / 192) % 96;
    int b = i / (192 * 96);
    int si = ii < 96 ? ii : ii - 96;
    size_t base = (size_t)b * 9216 + si * 96 + o;
    float p0 = w1l[base], p1 = w1l[73728 + base];
    float wp = 0.5f * (p0 + p1), wm = 0.5f * (p0 - p1);
    float q0 = w2l[base], q1 = w2l[73728 + base];
    float vp = 0.5f * (q0 + q1), vm = 0.5f * (q0 - q1);
    WB1k[i] = f2b(ii < 96 ? wp : wm);
    WB1n[i] = f2b(ii < 96 ? wm : wp);
    WB2[i] = f2b(ii < 96 ? vp : vm);
}

// ---------------- bf16 MFMA GEMM: out = A[M,K] * B[N,K]^T ----------------
// mode 0: fp32 out
// mode 1: bf16 out = gelu(acc + bias[n])
// mode 2: fp32 out = acc + bias[n] + extra[m*ldout+n]
__global__ __launch_bounds__(256) void gemm_bf16(const u16* __restrict__ A,
                                                 const u16* __restrict__ B,
                                                 const float* __restrict__ bias,
                                                 const float* __restrict__ extra,
                                                 void* __restrict__ out,
                                                 int M, int N, int K, int ldout, int mode) {
    __shared__ u16 As[4096];
    __shared__ u16 Bs[4096];
    int tid = threadIdx.x;
    int m0 = blockIdx.x * 128, n0 = blockIdx.y * 128;
    int srow = tid >> 2;
    int sk8 = (tid & 3) * 8;
    int ar0 = m0 + srow;        ar0 = ar0 < M ? ar0 : M - 1;
    int ar1 = m0 + 64 + srow;   ar1 = ar1 < M ? ar1 : M - 1;
    int br0 = n0 + srow;        br0 = br0 < N ? br0 : N - 1;
    int br1 = n0 + 64 + srow;   br1 = br1 < N ? br1 : N - 1;
    const u16* Ag0 = A + (size_t)ar0 * K + sk8;
    const u16* Ag1 = A + (size_t)ar1 * K + sk8;
    const u16* Bg0 = B + (size_t)br0 * K + sk8;
    const u16* Bg1 = B + (size_t)br1 * K + sk8;

    int lane = tid & 63, wave = tid >> 6;
    int wm = (wave & 1) * 64, wn = (wave >> 1) * 64;
    int lm = lane & 15, quad = lane >> 4;

    floatx4 acc[4][4];
    floatx4 z = {0.f, 0.f, 0.f, 0.f};
#pragma unroll
    for (int i = 0; i < 4; i++)
#pragma unroll
        for (int j = 0; j < 4; j++) acc[i][j] = z;

    for (int k0 = 0; k0 < K; k0 += 32) {
        __builtin_amdgcn_global_load_lds(GLP(Ag0 + k0), LDSP(As + tid * 8), 16, 0, 0);
        __builtin_amdgcn_global_load_lds(GLP(Ag1 + k0), LDSP(As + 2048 + tid * 8), 16, 0, 0);
        __builtin_amdgcn_global_load_lds(GLP(Bg0 + k0), LDSP(Bs + tid * 8), 16, 0, 0);
        __builtin_amdgcn_global_load_lds(GLP(Bg1 + k0), LDSP(Bs + 2048 + tid * 8), 16, 0, 0);
        __syncthreads();
        bf16x8 af[4], bf[4];
#pragma unroll
        for (int i = 0; i < 4; i++)
            af[i] = *(const bf16x8*)(As + (wm + i * 16 + lm) * 32 + quad * 8);
#pragma unroll
        for (int j = 0; j < 4; j++)
            bf[j] = *(const bf16x8*)(Bs + (wn + j * 16 + lm) * 32 + quad * 8);
#pragma unroll
        for (int i = 0; i < 4; i++)
#pragma unroll
            for (int j = 0; j < 4; j++)
                acc[i][j] = __builtin_amdgcn_mfma_f32_16x16x32_bf16(af[i], bf[j], acc[i][j], 0, 0, 0);
        __syncthreads();
    }

#pragma unroll
    for (int j = 0; j < 4; j++) {
        int n = n0 + wn + j * 16 + lm;
        if (n >= N) continue;
        float bn = (mode >= 1) ? bias[n] : 0.f;
#pragma unroll
        for (int i = 0; i < 4; i++) {
#pragma unroll
            for (int r = 0; r < 4; r++) {
                int m = m0 + wm + i * 16 + quad * 4 + r;
                if (m >= M) continue;
                float v = acc[i][j][r];
                size_t g = (size_t)m * ldout + n;
                if (mode == 0) {
                    ((float*)out)[g] = v;
                } else if (mode == 1) {
                    v += bn;
                    float gl = 0.5f * v * (1.0f + erff(v * 0.70710678118654752f));
                    ((u16*)out)[g] = f2b(gl);
                } else {
                    v += bn + extra[g];
                    ((float*)out)[g] = v;
                }
            }
        }
    }
}

// ---------------- generic fp32 tile GEMM (patch embed + head only) ----------------
__global__ __launch_bounds__(256) void gemm_f32(const float* __restrict__ A,
                                                const float* __restrict__ B,
                                                const float* __restrict__ bias,
                                                const float* __restrict__ extra,
                                                float* __restrict__ C,
                                                int M, int N, int K, int amode, int emode) {
    __shared__ float As[16][65];
    __shared__ float Bs[16][65];
    int tid = threadIdx.x;
    int tx = tid & 15, ty = tid >> 4;
    int m0 = blockIdx.x * 64, n0 = blockIdx.y * 64;
    float acc[4][4] = {};
    int lr = tid >> 2, lq = tid & 3;
    for (int k0 = 0; k0 < K; k0 += 16) {
        float4 av = make_float4(0.f, 0.f, 0.f, 0.f);
        int am = m0 + lr;
        if (am < M) {
            if (amode == 0) {
                av = *(const float4*)(A + (size_t)am * K + k0 + lq * 4);
            } else {
                int gh = am / 90, gw = am % 90;
                int k = k0 + lq * 4;
                int c = k >> 8, ph = (k >> 4) & 15, pw = k & 15;
                av = *(const float4*)(A + (size_t)c * 1036800 +
                                      (size_t)(gh * 16 + ph) * 1440 + gw * 16 + pw);
            }
        }
        As[lq * 4 + 0][lr] = av.x;
        As[lq * 4 + 1][lr] = av.y;
        As[lq * 4 + 2][lr] = av.z;
        As[lq * 4 + 3][lr] = av.w;
        float4 bv = make_float4(0.f, 0.f, 0.f, 0.f);
        int bn = n0 + lr;
        if (bn < N) bv = *(const float4*)(B + (size_t)bn * K + k0 + lq * 4);
        Bs[lq * 4 + 0][lr] = bv.x;
        Bs[lq * 4 + 1][lr] = bv.y;
        Bs[lq * 4 + 2][lr] = bv.z;
        Bs[lq * 4 + 3][lr] = bv.w;
        __syncthreads();
#pragma unroll
        for (int kk = 0; kk < 16; kk++) {
            float a_[4], b_[4];
#pragma unroll
            for (int i = 0; i < 4; i++) a_[i] = As[kk][ty + 16 * i];
#pragma unroll
            for (int j = 0; j < 4; j++) b_[j] = Bs[kk][tx + 16 * j];
#pragma unroll
            for (int i = 0; i < 4; i++)
#pragma unroll
                for (int j = 0; j < 4; j++) acc[i][j] += a_[i] * b_[j];
        }
        __syncthreads();
    }
#pragma unroll
    for (int i = 0; i < 4; i++) {
        int m = m0 + ty + 16 * i;
        if (m >= M) continue;
#pragma unroll
        for (int j = 0; j < 4; j++) {
            int n = n0 + tx + 16 * j;
            if (n >= N) continue;
            float v = acc[i][j];
            if (emode == 0) {
                v += bias[n] + extra[(size_t)m * N + n];
                C[(size_t)m * N + n] = v;
            } else {
                int ch = n % 20, q = n / 20;
                int pw = q & 15, ph = q >> 4;
                int gh = m / 90, gw = m % 90;
                C[(size_t)ch * 1036800 + (size_t)(gh * 16 + ph) * 1440 + gw * 16 + pw] = v;
            }
        }
    }
}

// ---------------- DFT along W ----------------
__global__ __launch_bounds__(256) void dft_w_kernel(const float* __restrict__ inre,
                                                    const float* __restrict__ inim,
                                                    float* __restrict__ outre,
                                                    float* __restrict__ outim,
                                                    const float* __restrict__ twc,
                                                    const float* __restrict__ tws,
                                                    int Win, int Jout, int modeA) {
    int h = blockIdx.x;
    int k0 = blockIdx.y * 32;
    __shared__ float sre[2880];
    __shared__ float sim[2880];
    for (int idx = threadIdx.x; idx < Win * 32; idx += 256) {
        int w = idx >> 5, kk = idx & 31;
        int k = k0 + kk;
        float vr = 0.f, vi = 0.f;
        if (k < 385) {
            size_t g = ((size_t)h * Win + w) * 385 + k;
            vr = inre[g];
            vi = inim[g];
        }
        sre[idx] = vr;
        sim[idx] = vi;
    }
    __syncthreads();
    for (int idx = threadIdx.x; idx < Jout * 32; idx += 256) {
        int j = idx >> 5, kk = idx & 31;
        int k = k0 + kk;
        if (k >= 385) continue;
        int wf = modeA ? (j < 23 ? j : j + 45) : j;
        float ar = 0.f, ai = 0.f;
        for (int ww = 0; ww < Win; ww++) {
            float cc = twc[wf * 90 + ww], ss = tws[wf * 90 + ww];
            float xr = sre[(ww << 5) | kk], xi = sim[(ww << 5) | kk];
            ar += xr * cc + xi * ss;
            ai += xi * cc - xr * ss;
        }
        size_t g = ((size_t)h * Jout + j) * 385 + k;
        outre[g] = ar;
        outim[g] = ai;
    }
}

// ---------------- DFT along H ----------------
__global__ __launch_bounds__(256) void dft_h_kernel(const float* __restrict__ inre,
                                                    const float* __restrict__ inim,
                                                    float* __restrict__ outre,
                                                    float* __restrict__ outim,
                                                    const float* __restrict__ thc,
                                                    const float* __restrict__ ths, int J) {
    int j = blockIdx.x;
    int k0 = blockIdx.y * 32;
    __shared__ float sre[1440];
    __shared__ float sim[1440];
    for (int idx = threadIdx.x; idx < 45 * 32; idx += 256) {
        int hh = idx >> 5, kk = idx & 31;
        int k = k0 + kk;
        float vr = 0.f, vi = 0.f;
        if (k < 385) {
            size_t g = ((size_t)hh * J + j) * 385 + k;
            vr = inre[g];
            vi = inim[g];
        }
        sre[idx] = vr;
        sim[idx] = vi;
    }
    __syncthreads();
    for (int idx = threadIdx.x; idx < 45 * 32; idx += 256) {
        int i = idx >> 5, kk = idx & 31;
        int k = k0 + kk;
        if (k >= 385) continue;
        float ar = 0.f, ai = 0.f;
        for (int hh = 0; hh < 45; hh++) {
            float cc = thc[i * 45 + hh], ss = ths[i * 45 + hh];
            float xr = sre[(hh << 5) | kk], xi = sim[(hh << 5) | kk];
            ar += xr * cc + xi * ss;
            ai += xi * cc - xr * ss;
        }
        size_t g = ((size_t)i * J + j) * 385 + k;
        outre[g] = ar;
        outim[g] = ai;
    }
}

// ---------------- build X = [a | n] per block (bf16) ----------------
__global__ __launch_bounds__(256) void build_an(const float* __restrict__ F3re,
                                                const float* __restrict__ F3im,
                                                const float* __restrict__ tln,
                                                u16* __restrict__ X) {
    int idx = blockIdx.x * 256 + threadIdx.x;
    if (idx >= NROW * 768) return;
    int c = idx % 768;
    int r = idx / 768;
    int h = r / KW, w0 = r % KW;
    int h2 = (45 - h) % 45, w2 = (90 - w0) % 90;
    float av;
    if (c <= 384) {
        size_t g = ((size_t)(h * 45 + w0)) * 385 + c;
        av = F3re[g] + F3im[g];
    } else {
        int k = 768 - c;
        int j2 = (w2 == 0) ? 0 : (w2 - 45);
        size_t g = ((size_t)(h2 * 45 + j2)) * 385 + k;
        av = F3re[g] - F3im[g];
    }
    float nv = tln[((size_t)(h2 * 90 + w2)) * 768 + c];
    int b = c / 96, o = c % 96;
    X[(size_t)r * 1536 + b * 192 + o] = f2b(av);
    X[(size_t)r * 1536 + b * 192 + 96 + o] = f2b(nv);
}

// ---------------- block-MLP stages via MFMA ----------------
// A = X + b*192, lda=1536 (bf16), B = WB + b*96*192 [96,192] bf16
// mode 1: o1k=relu(acc1+bA), o1n=relu(acc2+bB); Y[.,b,0:96]=o1k, Y[.,b,96:192]=o1n, Z[.,b,0:96]=o1n
// mode 2: o2k=acc+bA; Z[.,b,96:192]=bf16(o2k); O2K fp32
// mode 3: o2n=acc+bA; full=o2n+O2K; softthresh -> ybuf16[.,b*96+o]
__global__ __launch_bounds__(256) void blk_mfma(const u16* __restrict__ X,
                                                const u16* __restrict__ WBa,
                                                const u16* __restrict__ WBb,
                                                const float* __restrict__ biasA,
                                                const float* __restrict__ biasB,
                                                u16* __restrict__ Y, u16* __restrict__ Z,
                                                float* __restrict__ O2K,
                                                u16* __restrict__ ybuf16, int mode) {
    int b = blockIdx.x;
    int m0 = blockIdx.y * 64;
    int tid = threadIdx.x, lane = tid & 63, wave = tid >> 6;
    int lm = lane & 15, quad = lane >> 4;
    int row = m0 + wave * 16 + lm;
    int rowc = row < NROW ? row : NROW - 1;
    const u16* Ab = X + (size_t)rowc * 1536 + b * 192;
    const u16* Wa = WBa + (size_t)b * 96 * 192;
    const u16* Wb = WBb ? WBb + (size_t)b * 96 * 192 : nullptr;
    floatx4 acc[6], acc2[6];
    floatx4 z = {0.f, 0.f, 0.f, 0.f};
#pragma unroll
    for (int j = 0; j < 6; j++) { acc[j] = z; acc2[j] = z; }
#pragma unroll
    for (int k = 0; k < 6; k++) {
        bf16x8 a = *(const bf16x8*)(Ab + k * 32 + quad * 8);
#pragma unroll
        for (int j = 0; j < 6; j++) {
            bf16x8 w = *(const bf16x8*)(Wa + (size_t)(j * 16 + lm) * 192 + k * 32 + quad * 8);
            acc[j] = __builtin_amdgcn_mfma_f32_16x16x32_bf16(a, w, acc[j], 0, 0, 0);
            if (mode == 1) {
                bf16x8 w2 = *(const bf16x8*)(Wb + (size_t)(j * 16 + lm) * 192 + k * 32 + quad * 8);
                acc2[j] = __builtin_amdgcn_mfma_f32_16x16x32_bf16(a, w2, acc2[j], 0, 0, 0);
            }
        }
    }
#pragma unroll
    for (int j = 0; j < 6; j++) {
        int n = j * 16 + lm;
        float bA = biasA[b * 96 + n];
        float bB = (mode == 1) ? biasB[b * 96 + n] : 0.f;
#pragma unroll
        for (int r = 0; r < 4; r++) {
            int m = m0 + wave * 16 + quad * 4 + r;
            if (m >= NROW) continue;
            if (mode == 1) {
                float v1 = fmaxf(acc[j][r] + bA, 0.f);
                float v2 = fmaxf(acc2[j][r] + bB, 0.f);
                Y[(size_t)m * 1536 + b * 192 + n] = f2b(v1);
                Y[(size_t)m * 1536 + b * 192 + 96 + n] = f2b(v2);
                Z[(size_t)m * 1536 + b * 192 + n] = f2b(v2);
            } else if (mode == 2) {
                float v = acc[j][r] + bA;
                Z[(size_t)m * 1536 + b * 192 + 96 + n] = f2b(v);
                O2K[(size_t)m * 768 + b * 96 + n] = v;
            } else {
                float full = acc[j][r] + bA + O2K[(size_t)m * 768 + b * 96 + n];
                float v = (full > LAMF) ? (full - LAMF) : ((full < -LAMF) ? (full + LAMF) : 0.f);
                ybuf16[(size_t)m * 768 + b * 96 + n] = f2b(v);
            }
        }
    }
}

// ---------------- combine ----------------
__global__ __launch_bounds__(256) void afno_combine(const float* __restrict__ F4re,
                                                    const float* __restrict__ F4im,
                                                    const float* __restrict__ cur,
                                                    const float* __restrict__ tln,
                                                    float* __restrict__ mid) {
    int idx = blockIdx.x * 256 + threadIdx.x;
    if (idx >= 3110400) return;
    int c = idx % 768;
    int t = idx / 768;
    int h = t / 90, w0 = t % 90;
    float v;
    if (c <= 384) {
        size_t g = (size_t)t * 385 + c;
        v = F4re[g] + F4im[g];
    } else {
        int k = 768 - c;
        int h2 = (45 - h) % 45, w2 = (90 - w0) % 90;
        size_t g = ((size_t)(h2 * 90 + w2)) * 385 + k;
        v = F4re[g] - F4im[g];
    }
    mid[idx] = cur[idx] + tln[idx] + v * (1.0f / SZ_ALL);
}

// ---------------- host ----------------
extern "C" void kernel_launch(void* const* d_in, const int* in_sizes, int n_in,
                              void* d_out, int out_size, void* d_ws, size_t ws_size,
                              hipStream_t stream) {
    const float* x       = (const float*)d_in[0];
    const float* patch_w = (const float*)d_in[1];
    const float* patch_b = (const float*)d_in[2];
    const float* pos     = (const float*)d_in[3];
    const float* n1w     = (const float*)d_in[4];
    const float* n1b     = (const float*)d_in[5];
    const float* w1      = (const float*)d_in[6];
    const float* b1      = (const float*)d_in[7];
    const float* w2      = (const float*)d_in[8];
    const float* b2      = (const float*)d_in[9];
    const float* n2w     = (const float*)d_in[10];
    const float* n2b     = (const float*)d_in[11];
    const float* fc1w    = (const float*)d_in[12];
    const float* fc1b    = (const float*)d_in[13];
    const float* fc2w    = (const float*)d_in[14];
    const float* fc2b    = (const float*)d_in[15];
    const float* headw   = (const float*)d_in[16];
    float* out = (float*)d_out;
    float* wsp = (float*)d_ws;

    size_t off = 0;
    auto af_ = [&](size_t n) { float* p = wsp + off; off += (n + 3) & ~(size_t)3; return p; };
    auto au_ = [&](size_t n) { u16* p = (u16*)(wsp + off); off += ((n + 1) / 2 + 3) & ~(size_t)3; return p; };

    u16* TCc = au_(512 * 768);
    u16* TCs = au_(512 * 768);
    float* TWc = af_(8100);
    float* TWs = af_(8100);
    float* THc = af_(2025);
    float* THs = af_(2025);
    u16* WB1k = au_(147456);
    u16* WB1n = au_(147456);
    u16* WB2 = au_(147456);
    u16* fc1w16 = au_(2359296);
    u16* fc2w16 = au_(2359296);
    float* cur = af_(3110400);
    float* tln = af_(3110400);
    float* mid = af_(3110400);
    u16* tln16 = au_(3110400);
    u16* Xb = au_(1589760);
    u16* Yb = au_(1589760);
    u16* Zb = au_(1589760);
    float* O2K = af_(794880);
    u16* ybuf16 = au_(794880);
    float* F2re = af_(779625);
    float* F2im = af_(779625);
    float* F3re = af_(779625);
    float* F3im = af_(779625);
    float* P1re = af_(4 * 1559252);           // P-block; aliased by hidden16
    float* P1im = P1re + 1559252;
    float* P2re = P1im + 1559252;
    float* P2im = P2re + 1559252;
    u16* hidden16 = (u16*)P1re;               // 12,441,600 u16 = 6,220,800 f <= 6,237,008 f
    size_t need = off * sizeof(float);
    if (ws_size < need) return;

    init_tables<<<1536, 256, 0, stream>>>(TCc, TCs, TWc, TWs, THc, THs);

    // patch embed (fp32): cur = patches @ patch_w^T + patch_b + pos
    gemm_f32<<<dim3(64, 12), 256, 0, stream>>>(x, patch_w, patch_b, pos, cur,
                                               NTOK, 768, 5120, 1, 0);

    for (int l = 0; l < 12; l++) {
        const float* w1l = w1 + (size_t)l * 147456;
        const float* b1l = b1 + (size_t)l * 1536;
        const float* w2l = w2 + (size_t)l * 147456;
        const float* b2l = b2 + (size_t)l * 1536;

        cast_f2b<<<2304, 256, 0, stream>>>(fc1w + (size_t)l * 2359296, fc1w16, 2359296);
        cast_f2b<<<2304, 256, 0, stream>>>(fc2w + (size_t)l * 2359296, fc2w16, 2359296);
        wpm_prep<<<576, 256, 0, stream>>>(w1l, w2l, WB1k, WB1n, WB2);
        ln_kernel<<<NTOK, 256, 0, stream>>>(cur, n1w + l * 768, n1b + l * 768, tln, tln16);

        // DHT1: C-axis DFT (two bf16 GEMMs) -> W -> H
        gemm_bf16<<<dim3(32, 4), 256, 0, stream>>>(tln16, TCc, nullptr, nullptr, P1re,
                                                   NTOK, 385, 768, 385, 0);
        gemm_bf16<<<dim3(32, 4), 256, 0, stream>>>(tln16, TCs, nullptr, nullptr, P1im,
                                                   NTOK, 385, 768, 385, 0);
        dft_w_kernel<<<dim3(45, 13), 256, 0, stream>>>(P1re, P1im, F2re, F2im, TWc, TWs,
                                                       90, 45, 1);
        dft_h_kernel<<<dim3(45, 13), 256, 0, stream>>>(F2re, F2im, F3re, F3im, THc, THs, 45);
        build_an<<<(NROW * 768 + 255) / 256, 256, 0, stream>>>(F3re, F3im, tln, Xb);

        // block MLP (MFMA)
        blk_mfma<<<dim3(8, 17), 256, 0, stream>>>(Xb, WB1k, WB1n, b1l, b1l + 768,
                                                  Yb, Zb, nullptr, nullptr, 1);
        blk_mfma<<<dim3(8, 17), 256, 0, stream>>>(Yb, WB2, nullptr, b2l, nullptr,
                                                  nullptr, Zb, O2K, nullptr, 2);
        blk_mfma<<<dim3(8, 17), 256, 0, stream>>>(Zb, WB2, nullptr, b2l + 768, nullptr,
                                                  nullptr, nullptr, O2K, ybuf16, 3);

        // DHT2: C-axis DFT (1035 rows) -> W (23->90) -> H -> combine
        gemm_bf16<<<dim3(9, 4), 256, 0, stream>>>(ybuf16, TCc, nullptr, nullptr, F2re,
                                                  NROW, 385, 768, 385, 0);
        gemm_bf16<<<dim3(9, 4), 256, 0, stream>>>(ybuf16, TCs, nullptr, nullptr, F2im,
                                                  NROW, 385, 768, 385, 0);
        dft_w_kernel<<<dim3(45, 13), 256, 0, stream>>>(F2re, F2im, P1re, P1im, TWc, TWs,
                                                       23, 90, 0);
        dft_h_kernel<<<dim3(90, 13), 256, 0, stream>>>(P1re, P1im, P2re, P2im, THc, THs, 90);
        afno_combine<<<(3110400 + 255) / 256, 256, 0, stream>>>(P2re, P2im, cur, tln, mid);

        // MLP (bf16 MFMA)
        ln_kernel<<<NTOK, 256, 0, stream>>>(mid, n2w + l * 768, n2b + l * 768, tln, tln16);
        gemm_bf16<<<dim3(32, 24), 256, 0, stream>>>(tln16, fc1w16, fc1b + l * 3072, nullptr,
                                                    hidden16, NTOK, 3072, 768, 3072, 1);
        gemm_bf16<<<dim3(32, 6), 256, 0, stream>>>(hidden16, fc2w16, fc2b + l * 768, mid,
                                                   cur, NTOK, 768, 3072, 768, 2);
    }

    // head (fp32) + scatter to (20,720,1440)
    gemm_f32<<<dim3(64, 80), 256, 0, stream>>>(cur, headw, nullptr, nullptr, out,
                                               NTOK, 5120, 768, 0, 3);
}

// Round 3
// 5678.127 us; speedup vs baseline: 3.2223x; 1.2396x over previous
//
#include <hip/hip_runtime.h>
#include <math.h>

typedef __attribute__((ext_vector_type(4))) float floatx4;
typedef __attribute__((ext_vector_type(8))) short bf16x8;
typedef unsigned short u16;

#define NTOK 4050
#define KW 23
#define NROW 1035
#define SZ_ALL 3110400.0f
#define LAMF 0.01f
#define LD1 17344   // padded row length for D1/D2/D3 (>=17325, mult of 64)
#define LD4 34688   // padded row length for D4 (>=34650, mult of 64)

#define GLP(p) ((const __attribute__((address_space(1))) void*)(p))
#define LDSP(p) ((__attribute__((address_space(3))) void*)(p))

__device__ __forceinline__ u16 f2b(float f) {
    union { float f; unsigned int u; } x;
    x.f = f;
    unsigned int r = x.u + 0x7FFFu + ((x.u >> 16) & 1u);
    return (u16)(r >> 16);
}
__device__ __forceinline__ float b2f(u16 u) {
    union { unsigned int u; float f; } x;
    x.u = ((unsigned int)u) << 16;
    return x.f;
}

// ---------------- LN (norm1): fp32 out + bf16 out ----------------
__global__ __launch_bounds__(256) void ln_kernel(const float* __restrict__ x,
                                                 const float* __restrict__ w,
                                                 const float* __restrict__ b,
                                                 float* __restrict__ y,
                                                 u16* __restrict__ y16) {
    __shared__ float red[256];
    int t = blockIdx.x;
    int tid = threadIdx.x;
    const float* row = x + (size_t)t * 768;
    float v0 = row[tid], v1 = row[tid + 256], v2 = row[tid + 512];
    red[tid] = v0 + v1 + v2;
    __syncthreads();
    for (int off = 128; off > 0; off >>= 1) {
        if (tid < off) red[tid] += red[tid + off];
        __syncthreads();
    }
    float mean = red[0] * (1.0f / 768.0f);
    __syncthreads();
    float d0 = v0 - mean, d1 = v1 - mean, d2 = v2 - mean;
    red[tid] = d0 * d0 + d1 * d1 + d2 * d2;
    __syncthreads();
    for (int off = 128; off > 0; off >>= 1) {
        if (tid < off) red[tid] += red[tid + off];
        __syncthreads();
    }
    float rstd = rsqrtf(red[0] * (1.0f / 768.0f) + 1e-5f);
    float* yr = y + (size_t)t * 768;
    u16* ys = y16 + (size_t)t * 768;
    float o0 = d0 * rstd * w[tid] + b[tid];
    float o1 = d1 * rstd * w[tid + 256] + b[tid + 256];
    float o2 = d2 * rstd * w[tid + 512] + b[tid + 512];
    yr[tid] = o0; yr[tid + 256] = o1; yr[tid + 512] = o2;
    ys[tid] = f2b(o0); ys[tid + 256] = f2b(o1); ys[tid + 512] = f2b(o2);
}

// ---------------- fused afno-combine + LN (norm2) ----------------
// mid = cur + tlnA + idht/SZ ; tlnB16 = bf16(LN(mid))
__global__ __launch_bounds__(256) void ln2c_kernel(const float* __restrict__ F4re,
                                                   const float* __restrict__ F4im,
                                                   const float* __restrict__ cur,
                                                   const float* __restrict__ tlnA,
                                                   const float* __restrict__ w,
                                                   const float* __restrict__ b,
                                                   float* __restrict__ mid,
                                                   u16* __restrict__ y16) {
    __shared__ float red[256];
    int t = blockIdx.x;
    int tid = threadIdx.x;
    int h = t / 90, w0 = t % 90;
    int h2 = (45 - h) % 45, w2 = (90 - w0) % 90;
    float vv[3];
#pragma unroll
    for (int s = 0; s < 3; s++) {
        int c = tid + s * 256;
        float v;
        if (c <= 384) {
            size_t g = (size_t)h * 34650 + (size_t)w0 * 385 + c;
            v = F4re[g] + F4im[g];
        } else {
            int k = 768 - c;
            size_t g = (size_t)h2 * 34650 + (size_t)w2 * 385 + k;
            v = F4re[g] - F4im[g];
        }
        size_t gi = (size_t)t * 768 + c;
        v = cur[gi] + tlnA[gi] + v * (1.0f / SZ_ALL);
        mid[gi] = v;
        vv[s] = v;
    }
    red[tid] = vv[0] + vv[1] + vv[2];
    __syncthreads();
    for (int off = 128; off > 0; off >>= 1) {
        if (tid < off) red[tid] += red[tid + off];
        __syncthreads();
    }
    float mean = red[0] * (1.0f / 768.0f);
    __syncthreads();
    float d0 = vv[0] - mean, d1 = vv[1] - mean, d2 = vv[2] - mean;
    red[tid] = d0 * d0 + d1 * d1 + d2 * d2;
    __syncthreads();
    for (int off = 128; off > 0; off >>= 1) {
        if (tid < off) red[tid] += red[tid + off];
        __syncthreads();
    }
    float rstd = rsqrtf(red[0] * (1.0f / 768.0f) + 1e-5f);
    u16* ys = y16 + (size_t)t * 768;
    ys[tid]       = f2b(d0 * rstd * w[tid] + b[tid]);
    ys[tid + 256] = f2b(d1 * rstd * w[tid + 256] + b[tid + 256]);
    ys[tid + 512] = f2b(d2 * rstd * w[tid + 512] + b[tid + 512]);
}

// ---------------- tables ----------------
__global__ __launch_bounds__(256) void init_tables(u16* TCc, u16* TCs, float* T_W1,
                                                   float* T_H, float* T_W2) {
    int gid = blockIdx.x * 256 + threadIdx.x;
    const double TP = 6.283185307179586476925286766559;
    if (gid < 385 * 768) {
        int n = gid / 768, c = gid % 768;
        int r = (n * c) % 768;
        double a = TP * (double)r / 768.0;
        TCc[(size_t)n * 768 + c] = f2b((float)cos(a));
        TCs[(size_t)n * 768 + c] = f2b((float)(-sin(a)));
    }
    if (gid < 90 * 192) {  // T_W1 [90][192]
        int m = gid / 192, kp = gid % 192;
        int j = m % 45, im = m / 45;
        int jf = j < 23 ? j : j + 45;
        float val = 0.f;
        if (kp < 90) {
            double a = TP * (double)((jf * kp) % 90) / 90.0;
            val = im ? (float)(-sin(a)) : (float)cos(a);
        } else if (kp < 180) {
            int ww = kp - 90;
            double a = TP * (double)((jf * ww) % 90) / 90.0;
            val = im ? (float)cos(a) : (float)sin(a);
        }
        T_W1[gid] = val;
    }
    if (gid < 90 * 96) {  // T_H [90][96]
        int m = gid / 96, kp = gid % 96;
        int i = m % 45, im = m / 45;
        float val = 0.f;
        if (kp < 45) {
            double a = TP * (double)((i * kp) % 45) / 45.0;
            val = im ? (float)(-sin(a)) : (float)cos(a);
        } else if (kp < 90) {
            int hh = kp - 45;
            double a = TP * (double)((i * hh) % 45) / 45.0;
            val = im ? (float)cos(a) : (float)sin(a);
        }
        T_H[gid] = val;
    }
    if (gid < 180 * 48) {  // T_W2 [180][48]
        int m = gid / 48, kp = gid % 48;
        int j = m % 90, im = m / 90;
        float val = 0.f;
        if (kp < 23) {
            double a = TP * (double)((j * kp) % 90) / 90.0;
            val = im ? (float)(-sin(a)) : (float)cos(a);
        } else if (kp < 46) {
            int ww = kp - 23;
            double a = TP * (double)((j * ww) % 90) / 90.0;
            val = im ? (float)cos(a) : (float)sin(a);
        }
        T_W2[gid] = val;
    }
}

// ---------------- casts ----------------
__global__ __launch_bounds__(256) void cast_f2b(const float* __restrict__ in,
                                                u16* __restrict__ out, int n) {
    int i = (blockIdx.x * 256 + threadIdx.x) * 4;
    if (i >= n) return;
    float4 v = *(const float4*)(in + i);
    out[i] = f2b(v.x); out[i + 1] = f2b(v.y); out[i + 2] = f2b(v.z); out[i + 3] = f2b(v.w);
}

__global__ __launch_bounds__(256) void cast_split(const float* __restrict__ in,
                                                  u16* __restrict__ hi,
                                                  u16* __restrict__ lo, int n) {
    int i = (blockIdx.x * 256 + threadIdx.x) * 4;
    if (i >= n) return;
    float4 v = *(const float4*)(in + i);
    float vs[4] = {v.x, v.y, v.z, v.w};
#pragma unroll
    for (int s = 0; s < 4; s++) {
        u16 h = f2b(vs[s]);
        hi[i + s] = h;
        lo[i + s] = f2b(vs[s] - b2f(h));
    }
}

// ---------------- packed block-MLP weights ----------------
// WB1k=[Wp|Wm], WB1n=[Wm|Wp], WB2=[Vp|Vm], WB2s=[Vm|Vp]  (each [b][96 out][192 in] bf16)
__global__ __launch_bounds__(256) void wpm_prep(const float* __restrict__ w1l,
                                                const float* __restrict__ w2l,
                                                u16* WB1k, u16* WB1n, u16* WB2, u16* WB2s) {
    int i = blockIdx.x * 256 + threadIdx.x;
    if (i >= 147456) return;
    int ii = i % 192;
    int o = (i / 192) % 96;
    int b = i / (192 * 96);
    int si = ii < 96 ? ii : ii - 96;
    size_t base = (size_t)b * 9216 + si * 96 + o;
    float p0 = w1l[base], p1 = w1l[73728 + base];
    float wp = 0.5f * (p0 + p1), wm = 0.5f * (p0 - p1);
    float q0 = w2l[base], q1 = w2l[73728 + base];
    float vp = 0.5f * (q0 + q1), vm = 0.5f * (q0 - q1);
    WB1k[i] = f2b(ii < 96 ? wp : wm);
    WB1n[i] = f2b(ii < 96 ? wm : wp);
    WB2[i] = f2b(ii < 96 ? vp : vm);
    WB2s[i] = f2b(ii < 96 ? vm : vp);
}

// ---------------- bf16 MFMA GEMM: out = A[M,K] * B[N,K]^T ----------------
// amode 0: A bf16 matrix; amode 1: A = fp32 image (patch gather, K=5120)
// emode 0: fp32 direct  [m*ldout+n]
// emode 1: bf16 gelu(acc+bias)
// emode 2: fp32 acc+bias[n]+extra[m*ldout+n]
// emode 3: fp32 scatter g=(m%q)*ldd + (m/q)*385 + n   (DHT C-stage re-layout)
__global__ __launch_bounds__(256) void gemm_bf16(const void* __restrict__ Av,
                                                 const u16* __restrict__ B,
                                                 const float* __restrict__ bias,
                                                 const float* __restrict__ extra,
                                                 void* __restrict__ out,
                                                 int M, int N, int K, int ldout,
                                                 int amode, int emode, int q, int ldd) {
    __shared__ u16 As[4096];
    __shared__ u16 Bs[4096];
    int tid = threadIdx.x;
    int m0 = blockIdx.x * 128, n0 = blockIdx.y * 128;
    int srow = tid >> 2;
    int sk8 = (tid & 3) * 8;
    const u16* A = (const u16*)Av;
    const u16* Ag0 = nullptr; const u16* Ag1 = nullptr;
    if (amode == 0) {
        int ar0 = m0 + srow;        ar0 = ar0 < M ? ar0 : M - 1;
        int ar1 = m0 + 64 + srow;   ar1 = ar1 < M ? ar1 : M - 1;
        Ag0 = A + (size_t)ar0 * K + sk8;
        Ag1 = A + (size_t)ar1 * K + sk8;
    }
    int br0 = n0 + srow;        br0 = br0 < N ? br0 : N - 1;
    int br1 = n0 + 64 + srow;   br1 = br1 < N ? br1 : N - 1;
    const u16* Bg0 = B + (size_t)br0 * K + sk8;
    const u16* Bg1 = B + (size_t)br1 * K + sk8;

    int lane = tid & 63, wave = tid >> 6;
    int wm = (wave & 1) * 64, wn = (wave >> 1) * 64;
    int lm = lane & 15, quad = lane >> 4;

    floatx4 acc[4][4];
    floatx4 z = {0.f, 0.f, 0.f, 0.f};
#pragma unroll
    for (int i = 0; i < 4; i++)
#pragma unroll
        for (int j = 0; j < 4; j++) acc[i][j] = z;

    const float* img = (const float*)Av;
    for (int k0 = 0; k0 < K; k0 += 32) {
        if (amode == 0) {
            __builtin_amdgcn_global_load_lds(GLP(Ag0 + k0), LDSP(As + tid * 8), 16, 0, 0);
            __builtin_amdgcn_global_load_lds(GLP(Ag1 + k0), LDSP(As + 2048 + tid * 8), 16, 0, 0);
        } else {
#pragma unroll
            for (int half = 0; half < 2; half++) {
                int t = m0 + half * 64 + srow; t = t < M ? t : M - 1;
                int gh = t / 90, gw = t % 90;
                int k = k0 + sk8;
                int c = k >> 8, ph = (k >> 4) & 15, pw = k & 15;
                const float* p = img + (size_t)c * 1036800 +
                                 (size_t)(gh * 16 + ph) * 1440 + gw * 16 + pw;
                float4 u0 = *(const float4*)p;
                float4 u1 = *(const float4*)(p + 4);
                u16* dst = As + half * 2048 + tid * 8;
                dst[0] = f2b(u0.x); dst[1] = f2b(u0.y); dst[2] = f2b(u0.z); dst[3] = f2b(u0.w);
                dst[4] = f2b(u1.x); dst[5] = f2b(u1.y); dst[6] = f2b(u1.z); dst[7] = f2b(u1.w);
            }
        }
        __builtin_amdgcn_global_load_lds(GLP(Bg0 + k0), LDSP(Bs + tid * 8), 16, 0, 0);
        __builtin_amdgcn_global_load_lds(GLP(Bg1 + k0), LDSP(Bs + 2048 + tid * 8), 16, 0, 0);
        __syncthreads();
        bf16x8 af[4], bf[4];
#pragma unroll
        for (int i = 0; i < 4; i++)
            af[i] = *(const bf16x8*)(As + (wm + i * 16 + lm) * 32 + quad * 8);
#pragma unroll
        for (int j = 0; j < 4; j++)
            bf[j] = *(const bf16x8*)(Bs + (wn + j * 16 + lm) * 32 + quad * 8);
#pragma unroll
        for (int i = 0; i < 4; i++)
#pragma unroll
            for (int j = 0; j < 4; j++)
                acc[i][j] = __builtin_amdgcn_mfma_f32_16x16x32_bf16(af[i], bf[j], acc[i][j], 0, 0, 0);
        __syncthreads();
    }

#pragma unroll
    for (int j = 0; j < 4; j++) {
        int n = n0 + wn + j * 16 + lm;
        if (n >= N) continue;
        float bn = (emode == 1 || emode == 2) ? bias[n] : 0.f;
#pragma unroll
        for (int i = 0; i < 4; i++) {
#pragma unroll
            for (int r = 0; r < 4; r++) {
                int m = m0 + wm + i * 16 + quad * 4 + r;
                if (m >= M) continue;
                float v = acc[i][j][r];
                if (emode == 0) {
                    ((float*)out)[(size_t)m * ldout + n] = v;
                } else if (emode == 1) {
                    v += bn;
                    float gl = 0.5f * v * (1.0f + erff(v * 0.70710678118654752f));
                    ((u16*)out)[(size_t)m * ldout + n] = f2b(gl);
                } else if (emode == 2) {
                    size_t g = (size_t)m * ldout + n;
                    ((float*)out)[g] = v + bn + extra[g];
                } else {
                    size_t g = (size_t)(m % q) * ldd + (size_t)(m / q) * 385 + n;
                    ((float*)out)[g] = v;
                }
            }
        }
    }
}

// ---------------- split-bf16 GEMM (head): out = (Ahi+Alo)(Bhi+Blo)^T, drop lo*lo ----------------
// epilogue: head scatter to (20,720,1440)
__global__ __launch_bounds__(256) void gemm_split(const u16* __restrict__ Ahi,
                                                  const u16* __restrict__ Alo,
                                                  const u16* __restrict__ Bhi,
                                                  const u16* __restrict__ Blo,
                                                  float* __restrict__ out,
                                                  int M, int N, int K) {
    __shared__ u16 Ash[4096];
    __shared__ u16 Asl[4096];
    __shared__ u16 Bsh[4096];
    __shared__ u16 Bsl[4096];
    int tid = threadIdx.x;
    int m0 = blockIdx.x * 128, n0 = blockIdx.y * 128;
    int srow = tid >> 2, sk8 = (tid & 3) * 8;
    int ar0 = m0 + srow;        ar0 = ar0 < M ? ar0 : M - 1;
    int ar1 = m0 + 64 + srow;   ar1 = ar1 < M ? ar1 : M - 1;
    int br0 = n0 + srow;        br0 = br0 < N ? br0 : N - 1;
    int br1 = n0 + 64 + srow;   br1 = br1 < N ? br1 : N - 1;
    size_t a0 = (size_t)ar0 * K + sk8, a1 = (size_t)ar1 * K + sk8;
    size_t b0 = (size_t)br0 * K + sk8, b1 = (size_t)br1 * K + sk8;

    int lane = tid & 63, wave = tid >> 6;
    int wm = (wave & 1) * 64, wn = (wave >> 1) * 64;
    int lm = lane & 15, quad = lane >> 4;

    floatx4 acc[4][4];
    floatx4 z = {0.f, 0.f, 0.f, 0.f};
#pragma unroll
    for (int i = 0; i < 4; i++)
#pragma unroll
        for (int j = 0; j < 4; j++) acc[i][j] = z;

    for (int k0 = 0; k0 < K; k0 += 32) {
        __builtin_amdgcn_global_load_lds(GLP(Ahi + a0 + k0), LDSP(Ash + tid * 8), 16, 0, 0);
        __builtin_amdgcn_global_load_lds(GLP(Ahi + a1 + k0), LDSP(Ash + 2048 + tid * 8), 16, 0, 0);
        __builtin_amdgcn_global_load_lds(GLP(Alo + a0 + k0), LDSP(Asl + tid * 8), 16, 0, 0);
        __builtin_amdgcn_global_load_lds(GLP(Alo + a1 + k0), LDSP(Asl + 2048 + tid * 8), 16, 0, 0);
        __builtin_amdgcn_global_load_lds(GLP(Bhi + b0 + k0), LDSP(Bsh + tid * 8), 16, 0, 0);
        __builtin_amdgcn_global_load_lds(GLP(Bhi + b1 + k0), LDSP(Bsh + 2048 + tid * 8), 16, 0, 0);
        __builtin_amdgcn_global_load_lds(GLP(Blo + b0 + k0), LDSP(Bsl + tid * 8), 16, 0, 0);
        __builtin_amdgcn_global_load_lds(GLP(Blo + b1 + k0), LDSP(Bsl + 2048 + tid * 8), 16, 0, 0);
        __syncthreads();
        bf16x8 ah[4], al[4], bh[4], bl[4];
#pragma unroll
        for (int i = 0; i < 4; i++) {
            ah[i] = *(const bf16x8*)(Ash + (wm + i * 16 + lm) * 32 + quad * 8);
            al[i] = *(const bf16x8*)(Asl + (wm + i * 16 + lm) * 32 + quad * 8);
        }
#pragma unroll
        for (int j = 0; j < 4; j++) {
            bh[j] = *(const bf16x8*)(Bsh + (wn + j * 16 + lm) * 32 + quad * 8);
            bl[j] = *(const bf16x8*)(Bsl + (wn + j * 16 + lm) * 32 + quad * 8);
        }
#pragma unroll
        for (int i = 0; i < 4; i++)
#pragma unroll
            for (int j = 0; j < 4; j++) {
                acc[i][j] = __builtin_amdgcn_mfma_f32_16x16x32_bf16(al[i], bh[j], acc[i][j], 0, 0, 0);
                acc[i][j] = __builtin_amdgcn_mfma_f32_16x16x32_bf16(ah[i], bl[j], acc[i][j], 0, 0, 0);
                acc[i][j] = __builtin_amdgcn_mfma_f32_16x16x32_bf16(ah[i], bh[j], acc[i][j], 0, 0, 0);
            }
        __syncthreads();
    }

#pragma unroll
    for (int j = 0; j < 4; j++) {
        int n = n0 + wn + j * 16 + lm;
        if (n >= N) continue;
        int ch = n % 20, qq = n / 20;
        int pw = qq & 15, ph = qq >> 4;
#pragma unroll
        for (int i = 0; i < 4; i++) {
#pragma unroll
            for (int r = 0; r < 4; r++) {
                int m = m0 + wm + i * 16 + quad * 4 + r;
                if (m >= M) continue;
                int gh = m / 90, gw = m % 90;
                out[(size_t)ch * 1036800 + (size_t)(gh * 16 + ph) * 1440 + gw * 16 + pw] =
                    acc[i][j][r];
            }
        }
    }
}

// ---------------- fp32 DFT-stage GEMM: out = T[M,Kp] * D[Kp,N] ----------------
// scatter=0: g = m'*ldOut + n      (planes outA for m<M/2, outB for m>=M/2)
// scatter=1: g = (n/385)*ldOut + m'*385 + (n%385)
__global__ __launch_bounds__(256) void dft_gemm(const float* __restrict__ T,
                                                const float* __restrict__ D,
                                                float* __restrict__ outA,
                                                float* __restrict__ outB,
                                                int M, int N, int Kp, int ldD,
                                                int scatter, int ldOut) {
    __shared__ float Ts[16][68];
    __shared__ float Ds[16][132];
    int tid = threadIdx.x;
    int tx = tid & 15, ty = tid >> 4;
    int m0 = blockIdx.x * 64, n0 = blockIdx.y * 128;
    int lr = tid >> 2, lq = tid & 3;
    int dr = tid >> 4, dc = tid & 15;
    float acc[4][8] = {};
    for (int k0 = 0; k0 < Kp; k0 += 16) {
        int mr = m0 + lr; mr = mr < M ? mr : M - 1;
        float4 tv = *(const float4*)(T + (size_t)mr * Kp + k0 + lq * 4);
        Ts[lq * 4 + 0][lr] = tv.x;
        Ts[lq * 4 + 1][lr] = tv.y;
        Ts[lq * 4 + 2][lr] = tv.z;
        Ts[lq * 4 + 3][lr] = tv.w;
        const float* dp = D + (size_t)(k0 + dr) * ldD + n0 + dc * 4;
        float4 d0 = *(const float4*)dp;
        float4 d1 = *(const float4*)(dp + 64);
        Ds[dr][dc * 4 + 0] = d0.x; Ds[dr][dc * 4 + 1] = d0.y;
        Ds[dr][dc * 4 + 2] = d0.z; Ds[dr][dc * 4 + 3] = d0.w;
        Ds[dr][dc * 4 + 64] = d1.x; Ds[dr][dc * 4 + 65] = d1.y;
        Ds[dr][dc * 4 + 66] = d1.z; Ds[dr][dc * 4 + 67] = d1.w;
        __syncthreads();
#pragma unroll
        for (int kk = 0; kk < 16; kk++) {
            float a_[4], b_[8];
#pragma unroll
            for (int i = 0; i < 4; i++) a_[i] = Ts[kk][ty + 16 * i];
#pragma unroll
            for (int j = 0; j < 8; j++) b_[j] = Ds[kk][tx + 16 * j];
#pragma unroll
            for (int i = 0; i < 4; i++)
#pragma unroll
                for (int j = 0; j < 8; j++) acc[i][j] += a_[i] * b_[j];
        }
        __syncthreads();
    }
    int SP = M >> 1;
#pragma unroll
    for (int j = 0; j < 8; j++) {
        int n = n0 + tx + 16 * j;
        if (n >= N) continue;
        int h = n / 385, kk = n - h * 385;
#pragma unroll
        for (int i = 0; i < 4; i++) {
            int m = m0 + ty + 16 * i;
            if (m >= M) continue;
            int plane = m >= SP;
            int mp = plane ? m - SP : m;
            float* base = plane ? outB : outA;
            size_t g = scatter ? ((size_t)h * ldOut + (size_t)mp * 385 + kk)
                               : ((size_t)mp * ldOut + n);
            base[g] = acc[i][j];
        }
    }
}

// ---------------- build X = [a | n] per block (bf16) ----------------
__global__ __launch_bounds__(256) void build_an(const float* __restrict__ F3re,
                                                const float* __restrict__ F3im,
                                                const float* __restrict__ tln,
                                                u16* __restrict__ X) {
    int idx = blockIdx.x * 256 + threadIdx.x;
    if (idx >= NROW * 768) return;
    int c = idx % 768;
    int r = idx / 768;
    int h = r / KW, w0 = r % KW;
    int h2 = (45 - h) % 45, w2 = (90 - w0) % 90;
    float av;
    if (c <= 384) {
        size_t g = ((size_t)(h * 45 + w0)) * 385 + c;
        av = F3re[g] + F3im[g];
    } else {
        int k = 768 - c;
        int j2 = (w2 == 0) ? 0 : (w2 - 45);
        size_t g = ((size_t)(h2 * 45 + j2)) * 385 + k;
        av = F3re[g] - F3im[g];
    }
    float nv = tln[((size_t)(h2 * 90 + w2)) * 768 + c];
    int b = c / 96, o = c % 96;
    X[(size_t)r * 1536 + b * 192 + o] = f2b(av);
    X[(size_t)r * 1536 + b * 192 + 96 + o] = f2b(nv);
}

// ---------------- fused 3-stage block MLP (MFMA) ----------------
__global__ __launch_bounds__(256) void blk_fused(const u16* __restrict__ X,
                                                 const u16* __restrict__ WB1k,
                                                 const u16* __restrict__ WB1n,
                                                 const u16* __restrict__ WB2,
                                                 const u16* __restrict__ WB2s,
                                                 const float* __restrict__ b1l,
                                                 const float* __restrict__ b2l,
                                                 u16* __restrict__ ybuf16) {
    __shared__ u16 Ybuf[4][16 * 200];
    int b = blockIdx.x;
    int m0 = blockIdx.y * 64;
    int tid = threadIdx.x, lane = tid & 63, wave = tid >> 6;
    int lm = lane & 15, quad = lane >> 4;
    u16* Yw = &Ybuf[wave][0];

    int row = m0 + wave * 16 + lm;
    int rowc = row < NROW ? row : NROW - 1;
    const u16* Ab = X + (size_t)rowc * 1536 + b * 192;
    const u16* W1k = WB1k + (size_t)b * 18432;
    const u16* W1n = WB1n + (size_t)b * 18432;
    const u16* V2 = WB2 + (size_t)b * 18432;
    const u16* V2s = WB2s + (size_t)b * 18432;

    floatx4 z = {0.f, 0.f, 0.f, 0.f};
    floatx4 acc1[6], acc2[6];
#pragma unroll
    for (int j = 0; j < 6; j++) { acc1[j] = z; acc2[j] = z; }
    bf16x8 a[6];
#pragma unroll
    for (int k = 0; k < 6; k++) a[k] = *(const bf16x8*)(Ab + k * 32 + quad * 8);
#pragma unroll
    for (int k = 0; k < 6; k++)
#pragma unroll
        for (int j = 0; j < 6; j++) {
            bf16x8 w1 = *(const bf16x8*)(W1k + (size_t)(j * 16 + lm) * 192 + k * 32 + quad * 8);
            acc1[j] = __builtin_amdgcn_mfma_f32_16x16x32_bf16(a[k], w1, acc1[j], 0, 0, 0);
            bf16x8 w2 = *(const bf16x8*)(W1n + (size_t)(j * 16 + lm) * 192 + k * 32 + quad * 8);
            acc2[j] = __builtin_amdgcn_mfma_f32_16x16x32_bf16(a[k], w2, acc2[j], 0, 0, 0);
        }
    // stage1 epilogue -> Yw = [o1k | o1n]
#pragma unroll
    for (int j = 0; j < 6; j++) {
        int n = j * 16 + lm;
        float bA = b1l[b * 96 + n], bB = b1l[768 + b * 96 + n];
#pragma unroll
        for (int r = 0; r < 4; r++) {
            int mloc = quad * 4 + r;
            Yw[mloc * 200 + n] = f2b(fmaxf(acc1[j][r] + bA, 0.f));
            Yw[mloc * 200 + 96 + n] = f2b(fmaxf(acc2[j][r] + bB, 0.f));
        }
    }
    // stage2: o2k = [o1k|o1n]*[Vp|Vm] + b2k
    floatx4 acc3[6];
#pragma unroll
    for (int j = 0; j < 6; j++) acc3[j] = z;
    bf16x8 a2[6];
#pragma unroll
    for (int k = 0; k < 6; k++) a2[k] = *(const bf16x8*)(Yw + lm * 200 + k * 32 + quad * 8);
#pragma unroll
    for (int k = 0; k < 6; k++)
#pragma unroll
        for (int j = 0; j < 6; j++) {
            bf16x8 w = *(const bf16x8*)(V2 + (size_t)(j * 16 + lm) * 192 + k * 32 + quad * 8);
            acc3[j] = __builtin_amdgcn_mfma_f32_16x16x32_bf16(a2[k], w, acc3[j], 0, 0, 0);
        }
    float o2k[6][4];
#pragma unroll
    for (int j = 0; j < 6; j++) {
        int n = j * 16 + lm;
        float bA = b2l[b * 96 + n];
#pragma unroll
        for (int r = 0; r < 4; r++) {
            int mloc = quad * 4 + r;
            float v = acc3[j][r] + bA;
            o2k[j][r] = v;
            Yw[mloc * 200 + n] = f2b(v);  // Yw becomes [o2k | o1n]
        }
    }
    // stage3: o2n = [o2k|o1n]*[Vm|Vp] + b2n ; full = o2n + o2k ; soft-threshold
    floatx4 acc4[6];
#pragma unroll
    for (int j = 0; j < 6; j++) acc4[j] = z;
    bf16x8 a3[6];
#pragma unroll
    for (int k = 0; k < 6; k++) a3[k] = *(const bf16x8*)(Yw + lm * 200 + k * 32 + quad * 8);
#pragma unroll
    for (int k = 0; k < 6; k++)
#pragma unroll
        for (int j = 0; j < 6; j++) {
            bf16x8 w = *(const bf16x8*)(V2s + (size_t)(j * 16 + lm) * 192 + k * 32 + quad * 8);
            acc4[j] = __builtin_amdgcn_mfma_f32_16x16x32_bf16(a3[k], w, acc4[j], 0, 0, 0);
        }
#pragma unroll
    for (int j = 0; j < 6; j++) {
        int n = j * 16 + lm;
        float bB = b2l[768 + b * 96 + n];
#pragma unroll
        for (int r = 0; r < 4; r++) {
            int m = m0 + wave * 16 + quad * 4 + r;
            if (m >= NROW) continue;
            float full = acc4[j][r] + bB + o2k[j][r];
            float v = (full > LAMF) ? (full - LAMF) : ((full < -LAMF) ? (full + LAMF) : 0.f);
            ybuf16[(size_t)m * 768 + b * 96 + n] = f2b(v);
        }
    }
}

// ---------------- host ----------------
extern "C" void kernel_launch(void* const* d_in, const int* in_sizes, int n_in,
                              void* d_out, int out_size, void* d_ws, size_t ws_size,
                              hipStream_t stream) {
    const float* x       = (const float*)d_in[0];
    const float* patch_w = (const float*)d_in[1];
    const float* patch_b = (const float*)d_in[2];
    const float* pos     = (const float*)d_in[3];
    const float* n1w     = (const float*)d_in[4];
    const float* n1b     = (const float*)d_in[5];
    const float* w1      = (const float*)d_in[6];
    const float* b1      = (const float*)d_in[7];
    const float* w2      = (const float*)d_in[8];
    const float* b2      = (const float*)d_in[9];
    const float* n2w     = (const float*)d_in[10];
    const float* n2b     = (const float*)d_in[11];
    const float* fc1w    = (const float*)d_in[12];
    const float* fc1b    = (const float*)d_in[13];
    const float* fc2w    = (const float*)d_in[14];
    const float* fc2b    = (const float*)d_in[15];
    const float* headw   = (const float*)d_in[16];
    float* out = (float*)d_out;
    float* wsp = (float*)d_ws;

    size_t off = 0;
    auto af_ = [&](size_t n) { float* p = wsp + off; off += (n + 3) & ~(size_t)3; return p; };
    auto au_ = [&](size_t n) { u16* p = (u16*)(wsp + off); off += ((n + 1) / 2 + 3) & ~(size_t)3; return p; };

    u16* TCc = au_(512 * 768);
    u16* TCs = au_(512 * 768);
    float* T_W1 = af_(90 * 192);
    float* T_H  = af_(90 * 96);
    float* T_W2 = af_(180 * 48);
    u16* WB1k = au_(147456);
    u16* WB1n = au_(147456);
    u16* WB2  = au_(147456);
    u16* WB2s = au_(147456);
    u16* fc1w16 = au_(2359296);
    u16* fc2w16 = au_(2359296);
    float* cur = af_(3110400);
    float* mid = af_(3110400);
    float* tlnA = af_(3110400);
    u16* tlnA16 = au_(3110400);
    u16* tlnB16 = au_(3110400);
    u16* Xb = au_(1589760);
    u16* ybuf16 = au_(794880);
    float* F3re = af_(1559250);
    float* F3im = af_(1559250);
    float* F4re = af_(1559250);
    float* F4im = af_(1559250);
    float* SCR = af_(9400000);
    // DFT scratch inside SCR
    float* D1 = SCR;                         // [192][LD1]   (90 xr + 90 xi + pad)
    float* D2 = D1 + (size_t)192 * LD1;      // [96][LD1]    (45 xr + 45 xi + pad)
    float* D3 = D2 + (size_t)96 * LD1;       // [48][LD1]    (23 xr + 23 xi + pad)
    float* D4 = D3 + (size_t)48 * LD1;       // [96][LD4]    (45 xr + 45 xi + pad)
    u16* hidden16 = (u16*)SCR;               // 12.44M u16 = 6.22M f (MLP phase)
    u16* pw16 = (u16*)SCR;                   // patch phase
    u16* Chi = (u16*)SCR;                    // head phase
    u16* Clo = Chi + 3110400;
    u16* Hhi = Clo + 3110400;
    u16* Hlo = Hhi + 3932160;
    size_t need = off * sizeof(float);
    if (ws_size < need) return;

    init_tables<<<1536, 256, 0, stream>>>(TCc, TCs, T_W1, T_H, T_W2);

    // ---- patch embed: bf16 MFMA with inline image gather ----
    cast_f2b<<<3840, 256, 0, stream>>>(patch_w, pw16, 3932160);
    gemm_bf16<<<dim3(32, 6), 256, 0, stream>>>(x, pw16, patch_b, pos, cur,
                                               NTOK, 768, 5120, 768, 1, 2, 0, 0);

    for (int l = 0; l < 12; l++) {
        const float* w1l = w1 + (size_t)l * 147456;
        const float* b1l = b1 + (size_t)l * 1536;
        const float* w2l = w2 + (size_t)l * 147456;
        const float* b2l = b2 + (size_t)l * 1536;

        cast_f2b<<<2304, 256, 0, stream>>>(fc1w + (size_t)l * 2359296, fc1w16, 2359296);
        cast_f2b<<<2304, 256, 0, stream>>>(fc2w + (size_t)l * 2359296, fc2w16, 2359296);
        wpm_prep<<<576, 256, 0, stream>>>(w1l, w2l, WB1k, WB1n, WB2, WB2s);
        ln_kernel<<<NTOK, 256, 0, stream>>>(cur, n1w + l * 768, n1b + l * 768, tlnA, tlnA16);

        // DHT1: C-axis DFT -> D1 [w][h][k] layout (re/im planes)
        gemm_bf16<<<dim3(32, 4), 256, 0, stream>>>(tlnA16, TCc, nullptr, nullptr, D1,
                                                   NTOK, 385, 768, 0, 0, 3, 90, LD1);
        gemm_bf16<<<dim3(32, 4), 256, 0, stream>>>(tlnA16, TCs, nullptr, nullptr,
                                                   D1 + (size_t)90 * LD1,
                                                   NTOK, 385, 768, 0, 0, 3, 90, LD1);
        // W-axis (90 -> 45 selected) -> D2 [h][j][k]
        dft_gemm<<<dim3(2, 136), 256, 0, stream>>>(T_W1, D1, D2, D2 + (size_t)45 * LD1,
                                                   90, 17325, 192, LD1, 1, LD1);
        // H-axis (45 -> 45) -> F3 planes [i][j][k]
        dft_gemm<<<dim3(2, 136), 256, 0, stream>>>(T_H, D2, F3re, F3im,
                                                   90, 17325, 96, LD1, 0, 17325);
        build_an<<<(NROW * 768 + 255) / 256, 256, 0, stream>>>(F3re, F3im, tlnA, Xb);

        // fused block MLP
        blk_fused<<<dim3(8, 17), 256, 0, stream>>>(Xb, WB1k, WB1n, WB2, WB2s,
                                                   b1l, b2l, ybuf16);

        // DHT2: C-axis DFT -> D3 [w0][h][k]
        gemm_bf16<<<dim3(9, 4), 256, 0, stream>>>(ybuf16, TCc, nullptr, nullptr, D3,
                                                  NROW, 385, 768, 0, 0, 3, 23, LD1);
        gemm_bf16<<<dim3(9, 4), 256, 0, stream>>>(ybuf16, TCs, nullptr, nullptr,
                                                  D3 + (size_t)23 * LD1,
                                                  NROW, 385, 768, 0, 0, 3, 23, LD1);
        // W-axis (23 -> 90) -> D4 [h][j][k]
        dft_gemm<<<dim3(3, 136), 256, 0, stream>>>(T_W2, D3, D4, D4 + (size_t)45 * LD4,
                                                   180, 17325, 48, LD1, 1, LD4);
        // H-axis (45 -> 45) -> F4 planes [i][j][k]
        dft_gemm<<<dim3(2, 271), 256, 0, stream>>>(T_H, D4, F4re, F4im,
                                                   90, 34650, 96, LD4, 0, 34650);
        // combine + LN2 fused
        ln2c_kernel<<<NTOK, 256, 0, stream>>>(F4re, F4im, cur, tlnA,
                                              n2w + l * 768, n2b + l * 768, mid, tlnB16);

        // MLP
        gemm_bf16<<<dim3(32, 24), 256, 0, stream>>>(tlnB16, fc1w16, fc1b + l * 3072, nullptr,
                                                    hidden16, NTOK, 3072, 768, 3072, 0, 1, 0, 0);
        gemm_bf16<<<dim3(32, 6), 256, 0, stream>>>(hidden16, fc2w16, fc2b + l * 768, mid,
                                                   cur, NTOK, 768, 3072, 768, 0, 2, 0, 0);
    }

    // ---- head: split-bf16 GEMM + scatter ----
    cast_split<<<3038, 256, 0, stream>>>(cur, Chi, Clo, 3110400);
    cast_split<<<3840, 256, 0, stream>>>(headw, Hhi, Hlo, 3932160);
    gemm_split<<<dim3(32, 40), 256, 0, stream>>>(Chi, Clo, Hhi, Hlo, out,
                                                 NTOK, 5120, 768);
}